// Round 1
// baseline (583.228 us; speedup 1.0000x reference)
//
#include <hip/hip_runtime.h>

#define N_NODES 100000
#define N_EDGES 1600000
#define IN_DIM 128
#define HID 64
#define OUT_DIM 64

// ---------------- K1: h = x @ W_lin^T ----------------
// block 256; tile 32 rows x 64 cols; each thread 2 rows x 4 cols.
// LDS transposed layouts: xsT[k][r] stride 36, wsT[k][c] stride 68
// (strides chosen: 16B-aligned for vector reads; reads conflict-free,
// staging writes 8-way which is ~18% overhead here, acceptable round 1)
#define K1_ROWS 32
#define XPAD 36
#define WPAD 68

__global__ __launch_bounds__(256) void k1_linear(const float* __restrict__ x,
                                                 const float* __restrict__ W,
                                                 float* __restrict__ h) {
    __shared__ float xsT[IN_DIM * XPAD];   // 18,432 B
    __shared__ float wsT[IN_DIM * WPAD];   // 34,816 B
    const int tid = threadIdx.x;
    const int row0 = blockIdx.x * K1_ROWS;  // grid = 3125 exact, no guards

    for (int i = tid; i < HID * IN_DIM; i += 256) {
        int c = i >> 7, k = i & 127;
        wsT[k * WPAD + c] = W[i];
    }
    for (int i = tid; i < K1_ROWS * IN_DIM; i += 256) {
        int r = i >> 7, k = i & 127;
        xsT[k * XPAD + r] = x[row0 * IN_DIM + i];
    }
    __syncthreads();

    const int r0 = (tid & 15) * 2;
    const int c0 = (tid >> 4) * 4;
    float acc[2][4] = {};
#pragma unroll 4
    for (int k = 0; k < IN_DIM; ++k) {
        const float2 xv = *(const float2*)&xsT[k * XPAD + r0];
        const float4 wv = *(const float4*)&wsT[k * WPAD + c0];
        acc[0][0] += xv.x * wv.x; acc[0][1] += xv.x * wv.y;
        acc[0][2] += xv.x * wv.z; acc[0][3] += xv.x * wv.w;
        acc[1][0] += xv.y * wv.x; acc[1][1] += xv.y * wv.y;
        acc[1][2] += xv.y * wv.z; acc[1][3] += xv.y * wv.w;
    }
#pragma unroll
    for (int i2 = 0; i2 < 2; ++i2) {
        int row = row0 + r0 + i2;
        *(float4*)&h[row * HID + c0] =
            make_float4(acc[i2][0], acc[i2][1], acc[i2][2], acc[i2][3]);
    }
}

// ---------------- K1b: s = h@att[:64], d = h@att[64:] ----------------
// one wave per node; grid 25000 x 256 exact
__global__ __launch_bounds__(256) void k1b_sd(const float* __restrict__ h,
                                              const float* __restrict__ att,
                                              float* __restrict__ s,
                                              float* __restrict__ d) {
    const int node = (blockIdx.x * 256 + threadIdx.x) >> 6;
    const int lane = threadIdx.x & 63;
    float hv = h[node * HID + lane];
    float vs = hv * att[lane];
    float vd = hv * att[HID + lane];
#pragma unroll
    for (int off = 32; off; off >>= 1) {
        vs += __shfl_down(vs, off, 64);
        vd += __shfl_down(vd, off, 64);
    }
    if (lane == 0) { s[node] = vs; d[node] = vd; }
}

// ---------------- K2a: in-degree histogram ----------------
__global__ __launch_bounds__(256) void k2a_count(const int* __restrict__ ei,
                                                 int* __restrict__ counts) {
    int i = blockIdx.x * 256 + threadIdx.x;  // grid 6250 exact
    atomicAdd(&counts[ei[N_EDGES + i]], 1);
}

// ---------------- scan: exclusive prefix over counts ----------------
// single block, 1024 threads, wave-shfl scan; ~98 chunks
__global__ __launch_bounds__(1024) void k_scan(const int* __restrict__ counts,
                                               int* __restrict__ row_start,
                                               int* __restrict__ cursor) {
    __shared__ int wsum[16];
    __shared__ int carry_s;
    const int tid = threadIdx.x;
    const int lane = tid & 63;
    const int wv = tid >> 6;
    if (tid == 0) carry_s = 0;
    __syncthreads();
    for (int base = 0; base < N_NODES; base += 1024) {
        int i = base + tid;
        int v = (i < N_NODES) ? counts[i] : 0;
        int sc = v;
#pragma unroll
        for (int off = 1; off < 64; off <<= 1) {
            int t = __shfl_up(sc, off, 64);
            if (lane >= off) sc += t;
        }
        if (lane == 63) wsum[wv] = sc;
        __syncthreads();
        int wprefix = 0;
#pragma unroll
        for (int w = 0; w < 16; ++w) {
            int t = wsum[w];
            if (w < wv) wprefix += t;
        }
        int excl = carry_s + wprefix + (sc - v);
        if (i < N_NODES) { row_start[i] = excl; cursor[i] = excl; }
        __syncthreads();
        if (tid == 0) {
            int tot = 0;
#pragma unroll
            for (int w = 0; w < 16; ++w) tot += wsum[w];
            carry_s += tot;
        }
        __syncthreads();
    }
    if (tid == 0) row_start[N_NODES] = carry_s;
}

// ---------------- K2b: edge attention + CSR scatter ----------------
__global__ __launch_bounds__(256) void k2b_scatter(const int* __restrict__ ei,
                                                   const float* __restrict__ s,
                                                   const float* __restrict__ d,
                                                   int* __restrict__ cursor,
                                                   uint2* __restrict__ sorted) {
    int i = blockIdx.x * 256 + threadIdx.x;  // grid 6250 exact
    int srcv = ei[i];
    int dstv = ei[N_EDGES + i];
    float e = s[srcv] + d[dstv];
    e = (e > 0.f) ? e : 0.2f * e;            // leaky_relu(0.2)
    float ex = __expf(e);                    // shift-invariant: no global max needed
    int pos = atomicAdd(&cursor[dstv], 1);
    sorted[pos] = make_uint2((unsigned)srcv, __float_as_uint(ex));
}

// ---------------- K3: per-dst aggregate + fused relu + out GEMM ----------------
// one wave per node, lane = hidden channel; grid 25000 x 256 exact
__global__ __launch_bounds__(256) void k3_agg_out(const uint2* __restrict__ sorted,
                                                  const int* __restrict__ row_start,
                                                  const float* __restrict__ h,
                                                  const float* __restrict__ W_out,
                                                  const float* __restrict__ b_out,
                                                  float* __restrict__ out) {
    __shared__ float wo[OUT_DIM * 65];   // pad 65: row-major read 2-way (free)
    __shared__ float zs[4 * HID];
    const int tid = threadIdx.x;
    for (int i = tid; i < OUT_DIM * HID; i += 256) {
        int c = i >> 6, k = i & 63;
        wo[c * 65 + k] = W_out[i];
    }
    const int lane = tid & 63;
    const int wv = tid >> 6;
    const int node = blockIdx.x * 4 + wv;
    const int beg = row_start[node];
    const int end = row_start[node + 1];
    float acc = 0.f, sumex = 0.f;
    for (int j = beg; j < end; ++j) {
        uint2 v = sorted[j];                       // wave-uniform 8B load
        float ex = __uint_as_float(v.y);
        sumex += ex;
        acc += ex * h[v.x * 64u + lane];           // coalesced 256B gather
    }
    float z = acc / (sumex + 1e-9f);
    z = z > 0.f ? z : 0.f;                         // relu
    zs[wv * HID + lane] = z;
    __syncthreads();
    float o = b_out[lane];
#pragma unroll 8
    for (int k = 0; k < HID; ++k)
        o += zs[wv * HID + k] * wo[lane * 65 + k];
    out[node * 64 + lane] = o;
}

extern "C" void kernel_launch(void* const* d_in, const int* in_sizes, int n_in,
                              void* d_out, int out_size, void* d_ws, size_t ws_size,
                              hipStream_t stream) {
    const float* x     = (const float*)d_in[0];
    const int*   ei    = (const int*)d_in[1];
    const float* W_lin = (const float*)d_in[2];
    const float* att   = (const float*)d_in[3];
    const float* W_out = (const float*)d_in[4];
    const float* b_out = (const float*)d_in[5];
    float* out = (float*)d_out;

    // workspace layout (needs ~40.4 MB)
    char* ws = (char*)d_ws;
    float* h         = (float*)(ws);                          // 25,600,000 B
    float* s         = (float*)(ws + 25600000);               //    400,000 B
    float* d         = (float*)(ws + 26000000);               //    400,000 B
    int*   counts    = (int*)  (ws + 26400000);               //    400,000 B
    int*   row_start = (int*)  (ws + 26800000);               //    400,008 B (incl pad)
    int*   cursor    = (int*)  (ws + 27200008);               //    400,000 B
    uint2* sorted    = (uint2*)(ws + 27600008);               // 12,800,000 B

    hipMemsetAsync(counts, 0, N_NODES * sizeof(int), stream);

    k1_linear<<<N_NODES / K1_ROWS, 256, 0, stream>>>(x, W_lin, h);
    k1b_sd<<<N_NODES * 64 / 256, 256, 0, stream>>>(h, att, s, d);
    k2a_count<<<N_EDGES / 256, 256, 0, stream>>>(ei, counts);
    k_scan<<<1, 1024, 0, stream>>>(counts, row_start, cursor);
    k2b_scatter<<<N_EDGES / 256, 256, 0, stream>>>(ei, s, d, cursor, sorted);
    k3_agg_out<<<N_NODES / 4, 256, 0, stream>>>(sorted, row_start, h, W_out, b_out, out);
}

// Round 2
// 451.641 us; speedup vs baseline: 1.2914x; 1.2914x over previous
//
#include <hip/hip_runtime.h>

#define N_NODES 100000
#define N_EDGES 1600000
#define IN_DIM 128
#define HID 64
#define OUT_DIM 64

__device__ __forceinline__ unsigned bf16r(float f) {   // fp32 -> bf16 bits, RNE
    unsigned u = __float_as_uint(f);
    return (u + 0x7FFFu + ((u >> 16) & 1u)) >> 16;
}

// ---------------- K1: h2(bf16) = x @ W_lin^T ; s = h@att[:64]; d = h@att[64:] ----
// block 256; tile 32 rows x 64 cols; thread = 2 rows x 4 cols.
#define K1_ROWS 32
#define XPAD 36
#define WPAD 68

__global__ __launch_bounds__(256) void k1_linear(const float* __restrict__ x,
                                                 const float* __restrict__ W,
                                                 const float* __restrict__ att,
                                                 unsigned* __restrict__ h2,
                                                 float* __restrict__ s,
                                                 float* __restrict__ d) {
    __shared__ float xsT[IN_DIM * XPAD];   // 18,432 B
    __shared__ float wsT[IN_DIM * WPAD];   // 34,816 B
    __shared__ float satt[2 * HID];
    __shared__ float sacc[K1_ROWS], dacc[K1_ROWS];
    const int tid = threadIdx.x;
    const int row0 = blockIdx.x * K1_ROWS;  // grid = 3125 exact

    if (tid < 128) satt[tid] = att[tid];
    if (tid < K1_ROWS) { sacc[tid] = 0.f; dacc[tid] = 0.f; }
    for (int i = tid; i < HID * IN_DIM; i += 256) {
        int c = i >> 7, k = i & 127;
        wsT[k * WPAD + c] = W[i];
    }
    for (int i = tid; i < K1_ROWS * IN_DIM; i += 256) {
        int r = i >> 7, k = i & 127;
        xsT[k * XPAD + r] = x[row0 * IN_DIM + i];
    }
    __syncthreads();

    const int r0 = (tid & 15) * 2;
    const int c0 = (tid >> 4) * 4;
    float acc[2][4] = {};
#pragma unroll 4
    for (int k = 0; k < IN_DIM; ++k) {
        const float2 xv = *(const float2*)&xsT[k * XPAD + r0];
        const float4 wv = *(const float4*)&wsT[k * WPAD + c0];
        acc[0][0] += xv.x * wv.x; acc[0][1] += xv.x * wv.y;
        acc[0][2] += xv.x * wv.z; acc[0][3] += xv.x * wv.w;
        acc[1][0] += xv.y * wv.x; acc[1][1] += xv.y * wv.y;
        acc[1][2] += xv.y * wv.z; acc[1][3] += xv.y * wv.w;
    }
    // h2 (bf16 pairs, low half = even channel)
#pragma unroll
    for (int i2 = 0; i2 < 2; ++i2) {
        int row = row0 + r0 + i2;
        unsigned p0 = bf16r(acc[i2][0]) | (bf16r(acc[i2][1]) << 16);
        unsigned p1 = bf16r(acc[i2][2]) | (bf16r(acc[i2][3]) << 16);
        ((uint2*)h2)[(row * 32 + (c0 >> 1)) >> 1] = make_uint2(p0, p1);
    }
    // s,d partial dots (fp32), reduce across the 16 col-groups via LDS atomics
    float ps0 = 0.f, ps1 = 0.f, pd0 = 0.f, pd1 = 0.f;
#pragma unroll
    for (int j = 0; j < 4; ++j) {
        float as = satt[c0 + j], ad = satt[HID + c0 + j];
        ps0 += acc[0][j] * as; pd0 += acc[0][j] * ad;
        ps1 += acc[1][j] * as; pd1 += acc[1][j] * ad;
    }
    atomicAdd(&sacc[r0], ps0);     atomicAdd(&sacc[r0 + 1], ps1);
    atomicAdd(&dacc[r0], pd0);     atomicAdd(&dacc[r0 + 1], pd1);
    __syncthreads();
    if (tid < K1_ROWS) { s[row0 + tid] = sacc[tid]; d[row0 + tid] = dacc[tid]; }
}

// ---------------- K2a: in-degree histogram ----------------
__global__ __launch_bounds__(256) void k2a_count(const int* __restrict__ ei,
                                                 int* __restrict__ counts) {
    int i = blockIdx.x * 256 + threadIdx.x;  // grid 6250 exact
    atomicAdd(&counts[ei[N_EDGES + i]], 1);
}

// ---------------- scan: exclusive prefix over counts (int4-vectorized) -------
#define SCAN_V4 (N_NODES / 4)   // 25000, exact
__global__ __launch_bounds__(1024) void k_scan(const int* __restrict__ counts,
                                               int* __restrict__ row_start,
                                               int* __restrict__ cursor) {
    __shared__ int wsum[16];
    __shared__ int carry_s;
    const int tid = threadIdx.x;
    const int lane = tid & 63;
    const int wv = tid >> 6;
    if (tid == 0) carry_s = 0;
    __syncthreads();
    for (int base = 0; base < SCAN_V4; base += 1024) {
        int i4 = base + tid;
        int4 v = (i4 < SCAN_V4) ? ((const int4*)counts)[i4] : make_int4(0, 0, 0, 0);
        int s1 = v.x, s2 = s1 + v.y, s3 = s2 + v.z, s4 = s3 + v.w;
        int sc = s4;
#pragma unroll
        for (int off = 1; off < 64; off <<= 1) {
            int t = __shfl_up(sc, off, 64);
            if (lane >= off) sc += t;
        }
        if (lane == 63) wsum[wv] = sc;
        __syncthreads();
        int wprefix = 0;
#pragma unroll
        for (int w = 0; w < 16; ++w) {
            int t = wsum[w];
            if (w < wv) wprefix += t;
        }
        int excl = carry_s + wprefix + (sc - s4);
        if (i4 < SCAN_V4) {
            int4 o = make_int4(excl, excl + s1, excl + s2, excl + s3);
            ((int4*)row_start)[i4] = o;
            ((int4*)cursor)[i4] = o;
        }
        __syncthreads();
        if (tid == 0) {
            int tot = 0;
#pragma unroll
            for (int w = 0; w < 16; ++w) tot += wsum[w];
            carry_s += tot;
        }
        __syncthreads();
    }
    if (tid == 0) row_start[N_NODES] = carry_s;
}

// ---------------- K2b: edge attention + CSR scatter ----------------
__global__ __launch_bounds__(256) void k2b_scatter(const int* __restrict__ ei,
                                                   const float* __restrict__ s,
                                                   const float* __restrict__ d,
                                                   int* __restrict__ cursor,
                                                   uint2* __restrict__ sorted) {
    int i = blockIdx.x * 256 + threadIdx.x;  // grid 6250 exact
    int srcv = ei[i];
    int dstv = ei[N_EDGES + i];
    float e = s[srcv] + d[dstv];
    e = (e > 0.f) ? e : 0.2f * e;            // leaky_relu(0.2)
    float ex = __expf(e);                    // shift-invariant: no global max needed
    int pos = atomicAdd(&cursor[dstv], 1);
    sorted[pos] = make_uint2((unsigned)srcv, __float_as_uint(ex));
}

// ---------------- K3: per-dst aggregate (bf16 gather) + relu + out GEMM ------
// one wave per node; half-wave = edge slot, lane owns 2 channels (bf16x2).
__global__ __launch_bounds__(256) void k3_agg_out(const uint2* __restrict__ sorted,
                                                  const int* __restrict__ row_start,
                                                  const unsigned* __restrict__ h2,
                                                  const float* __restrict__ W_out,
                                                  const float* __restrict__ b_out,
                                                  float* __restrict__ out) {
    __shared__ float wo[OUT_DIM * 65];
    __shared__ float zs[4 * HID];
    const int tid = threadIdx.x;
    for (int i = tid; i < OUT_DIM * HID; i += 256) {
        int c = i >> 6, k = i & 63;
        wo[c * 65 + k] = W_out[i];
    }
    const int lane = tid & 63;
    const int wv = tid >> 6;
    const int l32 = lane & 31;
    const int hw = lane >> 5;
    const int node = blockIdx.x * 4 + wv;
    const int beg = row_start[node];
    const int end = row_start[node + 1];
    float a0 = 0.f, a1 = 0.f, se = 0.f;
    int j = beg + hw;
    for (; j + 2 < end; j += 4) {            // 4 edges in flight per wave
        uint2 r0 = sorted[j];
        uint2 r1 = sorted[j + 2];
        unsigned g0 = h2[r0.x * 32u + l32];
        unsigned g1 = h2[r1.x * 32u + l32];
        float e0 = __uint_as_float(r0.y), e1 = __uint_as_float(r1.y);
        se += e0 + e1;
        a0 += e0 * __uint_as_float(g0 << 16) + e1 * __uint_as_float(g1 << 16);
        a1 += e0 * __uint_as_float(g0 & 0xFFFF0000u) + e1 * __uint_as_float(g1 & 0xFFFF0000u);
    }
    for (; j < end; j += 2) {                // tail
        uint2 r = sorted[j];
        unsigned g = h2[r.x * 32u + l32];
        float e = __uint_as_float(r.y);
        se += e;
        a0 += e * __uint_as_float(g << 16);
        a1 += e * __uint_as_float(g & 0xFFFF0000u);
    }
    a0 += __shfl_xor(a0, 32, 64);
    a1 += __shfl_xor(a1, 32, 64);
    se += __shfl_xor(se, 32, 64);
    float inv = 1.f / (se + 1e-9f);
    float z0 = fmaxf(a0 * inv, 0.f);
    float z1 = fmaxf(a1 * inv, 0.f);
    if (hw == 0) {
        zs[wv * HID + 2 * l32]     = z0;
        zs[wv * HID + 2 * l32 + 1] = z1;
    }
    __syncthreads();
    float o = b_out[lane];
#pragma unroll 8
    for (int k = 0; k < HID; ++k)
        o += zs[wv * HID + k] * wo[lane * 65 + k];
    out[node * 64 + lane] = o;
}

extern "C" void kernel_launch(void* const* d_in, const int* in_sizes, int n_in,
                              void* d_out, int out_size, void* d_ws, size_t ws_size,
                              hipStream_t stream) {
    const float* x     = (const float*)d_in[0];
    const int*   ei    = (const int*)d_in[1];
    const float* W_lin = (const float*)d_in[2];
    const float* att   = (const float*)d_in[3];
    const float* W_out = (const float*)d_in[4];
    const float* b_out = (const float*)d_in[5];
    float* out = (float*)d_out;

    // workspace layout (~27.6 MB, all 16B-aligned)
    char* ws = (char*)d_ws;
    unsigned* h2        = (unsigned*)(ws);                    // 12,800,000 B (bf16 h)
    float*    s         = (float*)(ws + 12800000);            //    400,000 B
    float*    d         = (float*)(ws + 13200000);            //    400,000 B
    int*      counts    = (int*)  (ws + 13600000);            //    400,000 B
    int*      row_start = (int*)  (ws + 14000000);            //    400,016 B
    int*      cursor    = (int*)  (ws + 14400016);            //    400,000 B
    uint2*    sorted    = (uint2*)(ws + 14800016);            // 12,800,000 B

    hipMemsetAsync(counts, 0, N_NODES * sizeof(int), stream);

    k1_linear<<<N_NODES / K1_ROWS, 256, 0, stream>>>(x, W_lin, att, h2, s, d);
    k2a_count<<<N_EDGES / 256, 256, 0, stream>>>(ei, counts);
    k_scan<<<1, 1024, 0, stream>>>(counts, row_start, cursor);
    k2b_scatter<<<N_EDGES / 256, 256, 0, stream>>>(ei, s, d, cursor, sorted);
    k3_agg_out<<<N_NODES / 4, 256, 0, stream>>>(sorted, row_start, h2, W_out, b_out, out);
}

// Round 3
// 430.599 us; speedup vs baseline: 1.3545x; 1.0489x over previous
//
#include <hip/hip_runtime.h>

#define N_NODES 100000
#define N_EDGES 1600000
#define IN_DIM 128
#define HID 64
#define OUT_DIM 64

__device__ __forceinline__ unsigned bf16r(float f) {   // fp32 -> bf16 bits, RNE
    unsigned u = __float_as_uint(f);
    return (u + 0x7FFFu + ((u >> 16) & 1u)) >> 16;
}

// ---------------- K1: h2(bf16) = x @ W_lin^T ; s = h@att[:64]; d = h@att[64:] ----
#define K1_ROWS 32
#define XPAD 36
#define WPAD 68

__global__ __launch_bounds__(256) void k1_linear(const float* __restrict__ x,
                                                 const float* __restrict__ W,
                                                 const float* __restrict__ att,
                                                 unsigned* __restrict__ h2,
                                                 float* __restrict__ s,
                                                 float* __restrict__ d) {
    __shared__ float xsT[IN_DIM * XPAD];   // 18,432 B
    __shared__ float wsT[IN_DIM * WPAD];   // 34,816 B
    __shared__ float satt[2 * HID];
    __shared__ float sacc[K1_ROWS], dacc[K1_ROWS];
    const int tid = threadIdx.x;
    const int row0 = blockIdx.x * K1_ROWS;  // grid = 3125 exact

    if (tid < 128) satt[tid] = att[tid];
    if (tid < K1_ROWS) { sacc[tid] = 0.f; dacc[tid] = 0.f; }
    for (int i = tid; i < HID * IN_DIM; i += 256) {
        int c = i >> 7, k = i & 127;
        wsT[k * WPAD + c] = W[i];
    }
    for (int i = tid; i < K1_ROWS * IN_DIM; i += 256) {
        int r = i >> 7, k = i & 127;
        xsT[k * XPAD + r] = x[row0 * IN_DIM + i];
    }
    __syncthreads();

    const int r0 = (tid & 15) * 2;
    const int c0 = (tid >> 4) * 4;
    float acc[2][4] = {};
#pragma unroll 4
    for (int k = 0; k < IN_DIM; ++k) {
        const float2 xv = *(const float2*)&xsT[k * XPAD + r0];
        const float4 wv = *(const float4*)&wsT[k * WPAD + c0];
        acc[0][0] += xv.x * wv.x; acc[0][1] += xv.x * wv.y;
        acc[0][2] += xv.x * wv.z; acc[0][3] += xv.x * wv.w;
        acc[1][0] += xv.y * wv.x; acc[1][1] += xv.y * wv.y;
        acc[1][2] += xv.y * wv.z; acc[1][3] += xv.y * wv.w;
    }
    // h2 (bf16 pairs): h2v[row*16 + q] holds channels 4q..4q+3
#pragma unroll
    for (int i2 = 0; i2 < 2; ++i2) {
        int row = row0 + r0 + i2;
        unsigned p0 = bf16r(acc[i2][0]) | (bf16r(acc[i2][1]) << 16);
        unsigned p1 = bf16r(acc[i2][2]) | (bf16r(acc[i2][3]) << 16);
        ((uint2*)h2)[row * 16 + (c0 >> 2)] = make_uint2(p0, p1);
    }
    // s,d partial dots (fp32), reduce across the 16 col-groups via LDS atomics
    float ps0 = 0.f, ps1 = 0.f, pd0 = 0.f, pd1 = 0.f;
#pragma unroll
    for (int j = 0; j < 4; ++j) {
        float as = satt[c0 + j], ad = satt[HID + c0 + j];
        ps0 += acc[0][j] * as; pd0 += acc[0][j] * ad;
        ps1 += acc[1][j] * as; pd1 += acc[1][j] * ad;
    }
    atomicAdd(&sacc[r0], ps0);     atomicAdd(&sacc[r0 + 1], ps1);
    atomicAdd(&dacc[r0], pd0);     atomicAdd(&dacc[r0 + 1], pd1);
    __syncthreads();
    if (tid < K1_ROWS) { s[row0 + tid] = sacc[tid]; d[row0 + tid] = dacc[tid]; }
}

// ---------------- K2a: in-degree histogram ----------------
__global__ __launch_bounds__(256) void k2a_count(const int* __restrict__ ei,
                                                 int* __restrict__ counts) {
    int i = blockIdx.x * 256 + threadIdx.x;  // grid 6250 exact
    atomicAdd(&counts[ei[N_EDGES + i]], 1);
}

// ---------------- scan: exclusive prefix over counts (int4-vectorized) -------
#define SCAN_V4 (N_NODES / 4)   // 25000, exact
__global__ __launch_bounds__(1024) void k_scan(const int* __restrict__ counts,
                                               int* __restrict__ row_start,
                                               int* __restrict__ cursor) {
    __shared__ int wsum[16];
    __shared__ int carry_s;
    const int tid = threadIdx.x;
    const int lane = tid & 63;
    const int wv = tid >> 6;
    if (tid == 0) carry_s = 0;
    __syncthreads();
    for (int base = 0; base < SCAN_V4; base += 1024) {
        int i4 = base + tid;
        int4 v = (i4 < SCAN_V4) ? ((const int4*)counts)[i4] : make_int4(0, 0, 0, 0);
        int s1 = v.x, s2 = s1 + v.y, s3 = s2 + v.z, s4 = s3 + v.w;
        int sc = s4;
#pragma unroll
        for (int off = 1; off < 64; off <<= 1) {
            int t = __shfl_up(sc, off, 64);
            if (lane >= off) sc += t;
        }
        if (lane == 63) wsum[wv] = sc;
        __syncthreads();
        int wprefix = 0;
#pragma unroll
        for (int w = 0; w < 16; ++w) {
            int t = wsum[w];
            if (w < wv) wprefix += t;
        }
        int excl = carry_s + wprefix + (sc - s4);
        if (i4 < SCAN_V4) {
            int4 o = make_int4(excl, excl + s1, excl + s2, excl + s3);
            ((int4*)row_start)[i4] = o;
            ((int4*)cursor)[i4] = o;
        }
        __syncthreads();
        if (tid == 0) {
            int tot = 0;
#pragma unroll
            for (int w = 0; w < 16; ++w) tot += wsum[w];
            carry_s += tot;
        }
        __syncthreads();
    }
    if (tid == 0) row_start[N_NODES] = carry_s;
}

// ---------------- K2b: edge attention + CSR scatter ----------------
__global__ __launch_bounds__(256) void k2b_scatter(const int* __restrict__ ei,
                                                   const float* __restrict__ s,
                                                   const float* __restrict__ d,
                                                   int* __restrict__ cursor,
                                                   uint2* __restrict__ sorted) {
    int i = blockIdx.x * 256 + threadIdx.x;  // grid 6250 exact
    int srcv = ei[i];
    int dstv = ei[N_EDGES + i];
    float e = s[srcv] + d[dstv];
    e = (e > 0.f) ? e : 0.2f * e;            // leaky_relu(0.2)
    float ex = __expf(e);                    // shift-invariant: no global max needed
    int pos = atomicAdd(&cursor[dstv], 1);
    sorted[pos] = make_uint2((unsigned)srcv, __float_as_uint(ex));
}

// ---------------- K3: per-dst aggregate (bf16 gather) + relu + out GEMM ------
// one wave per node; 16-lane edge groups (4 edges/wave) x unroll 2 = 8 in flight.
// lane owns 4 channels via one uint2 (bf16x4) gather.
__global__ __launch_bounds__(256) void k3_agg_out(const uint2* __restrict__ sorted,
                                                  const int* __restrict__ row_start,
                                                  const uint2* __restrict__ h2v,
                                                  const float* __restrict__ W_out,
                                                  const float* __restrict__ b_out,
                                                  float* __restrict__ out) {
    __shared__ float wo[OUT_DIM * 65];
    __shared__ float zs[4 * HID];
    const int tid = threadIdx.x;
    for (int i = tid; i < OUT_DIM * HID; i += 256) {
        int c = i >> 6, k = i & 63;
        wo[c * 65 + k] = W_out[i];
    }
    const int lane = tid & 63;
    const int wv = tid >> 6;
    const int l16 = lane & 15;   // uint2 index within row (channels 4*l16..+3)
    const int grp = lane >> 4;   // edge slot 0..3
    const int node = blockIdx.x * 4 + wv;
    const int beg = row_start[node];
    const int end = row_start[node + 1];
    float a0 = 0.f, a1 = 0.f, a2 = 0.f, a3 = 0.f, se = 0.f;
    int j = beg + grp;
    for (; j + 4 < end; j += 8) {            // 8 edges in flight per wave
        uint2 r0 = sorted[j];
        uint2 r1 = sorted[j + 4];
        uint2 g0 = h2v[r0.x * 16u + l16];
        uint2 g1 = h2v[r1.x * 16u + l16];
        float e0 = __uint_as_float(r0.y), e1 = __uint_as_float(r1.y);
        se += e0 + e1;
        a0 += e0 * __uint_as_float(g0.x << 16)        + e1 * __uint_as_float(g1.x << 16);
        a1 += e0 * __uint_as_float(g0.x & 0xFFFF0000u) + e1 * __uint_as_float(g1.x & 0xFFFF0000u);
        a2 += e0 * __uint_as_float(g0.y << 16)        + e1 * __uint_as_float(g1.y << 16);
        a3 += e0 * __uint_as_float(g0.y & 0xFFFF0000u) + e1 * __uint_as_float(g1.y & 0xFFFF0000u);
    }
    if (j < end) {                           // tail (at most one per group)
        uint2 r = sorted[j];
        uint2 g = h2v[r.x * 16u + l16];
        float e = __uint_as_float(r.y);
        se += e;
        a0 += e * __uint_as_float(g.x << 16);
        a1 += e * __uint_as_float(g.x & 0xFFFF0000u);
        a2 += e * __uint_as_float(g.y << 16);
        a3 += e * __uint_as_float(g.y & 0xFFFF0000u);
    }
    // reduce across the 4 edge groups (xor over grp bits = lane bits 4,5)
    a0 += __shfl_xor(a0, 16, 64); a0 += __shfl_xor(a0, 32, 64);
    a1 += __shfl_xor(a1, 16, 64); a1 += __shfl_xor(a1, 32, 64);
    a2 += __shfl_xor(a2, 16, 64); a2 += __shfl_xor(a2, 32, 64);
    a3 += __shfl_xor(a3, 16, 64); a3 += __shfl_xor(a3, 32, 64);
    se += __shfl_xor(se, 16, 64); se += __shfl_xor(se, 32, 64);
    float inv = 1.f / (se + 1e-9f);
    if (grp == 0) {
        float4 z = make_float4(fmaxf(a0 * inv, 0.f), fmaxf(a1 * inv, 0.f),
                               fmaxf(a2 * inv, 0.f), fmaxf(a3 * inv, 0.f));
        *(float4*)&zs[wv * HID + 4 * l16] = z;
    }
    __syncthreads();
    float o = b_out[lane];
#pragma unroll 8
    for (int k = 0; k < HID; ++k)
        o += zs[wv * HID + k] * wo[lane * 65 + k];
    out[node * 64 + lane] = o;
}

extern "C" void kernel_launch(void* const* d_in, const int* in_sizes, int n_in,
                              void* d_out, int out_size, void* d_ws, size_t ws_size,
                              hipStream_t stream) {
    const float* x     = (const float*)d_in[0];
    const int*   ei    = (const int*)d_in[1];
    const float* W_lin = (const float*)d_in[2];
    const float* att   = (const float*)d_in[3];
    const float* W_out = (const float*)d_in[4];
    const float* b_out = (const float*)d_in[5];
    float* out = (float*)d_out;

    // workspace layout (~27.6 MB, all 16B-aligned)
    char* ws = (char*)d_ws;
    unsigned* h2        = (unsigned*)(ws);                    // 12,800,000 B (bf16 h)
    float*    s         = (float*)(ws + 12800000);            //    400,000 B
    float*    d         = (float*)(ws + 13200000);            //    400,000 B
    int*      counts    = (int*)  (ws + 13600000);            //    400,000 B
    int*      row_start = (int*)  (ws + 14000000);            //    400,016 B
    int*      cursor    = (int*)  (ws + 14400016);            //    400,000 B
    uint2*    sorted    = (uint2*)(ws + 14800016);            // 12,800,000 B

    hipMemsetAsync(counts, 0, N_NODES * sizeof(int), stream);

    k1_linear<<<N_NODES / K1_ROWS, 256, 0, stream>>>(x, W_lin, att, h2, s, d);
    k2a_count<<<N_EDGES / 256, 256, 0, stream>>>(ei, counts);
    k_scan<<<1, 1024, 0, stream>>>(counts, row_start, cursor);
    k2b_scatter<<<N_EDGES / 256, 256, 0, stream>>>(ei, s, d, cursor, sorted);
    k3_agg_out<<<N_NODES / 4, 256, 0, stream>>>(sorted, row_start, (const uint2*)h2, W_out, b_out, out);
}